// Round 3
// baseline (405.659 us; speedup 1.0000x reference)
//
#include <hip/hip_runtime.h>
#include <hip/hip_bf16.h>

typedef _Float16 half4_t __attribute__((ext_vector_type(4)));
typedef float    float4_t __attribute__((ext_vector_type(4)));

#define MFMA16(a, b, c) __builtin_amdgcn_mfma_f32_16x16x16f16((a), (b), (c), 0, 0, 0)

constexpr int Bb = 1024, Ee = 512;
constexpr int EC = 32;                 // e-chunk
constexpr int NCH = Ee / EC;           // 16
constexpr int MP = 36;                 // sM row stride (halves)
constexpr int SP = 65;                 // sS row stride (f32)
constexpr int PP = 68;                 // sP row stride (halves)
constexpr long CTX = (long)Bb * 64 * Ee;

// ---- pre-pass: pack W (f32 [e][f]) into A-fragment-layout fp16 ----
// W2[((ft*32 + ks)*64 + lane)*4 + j] = W[ks*16 + q4(lane) + j][ft*16 + r16(lane)]
__global__ void w_pack(const float* __restrict__ W, _Float16* __restrict__ W2) {
    const int t    = blockIdx.x * 256 + threadIdx.x;   // 65536 threads
    const int lane = t & 63, grp = t >> 6;
    const int ks   = grp & 31, ft = grp >> 5;
    const int r16  = lane & 15, q4 = (lane >> 4) * 4;
    half4_t h;
    #pragma unroll
    for (int j = 0; j < 4; ++j)
        h[j] = (_Float16)W[(long)(ks * 16 + q4 + j) * 512 + ft * 16 + r16];
    *(half4_t*)(W2 + (long)t * 4) = h;
}

__global__ __launch_bounds__(512, 4)
void ovo_main(const float* __restrict__ o1, const float* __restrict__ o2,
              const float* __restrict__ o3, const float* __restrict__ qm,
              const _Float16* __restrict__ W2, float* __restrict__ out)
{
    __shared__ _Float16 sM[2][64 * MP];   // mean chunk fp16 [h][e'], double-buffered
    __shared__ float    sS[64 * SP];      // score f32 [h][g]
    __shared__ _Float16 sP[64 * PP];      // attn fp16 [h][g]

    const int b    = blockIdx.x;
    const int t    = threadIdx.x;
    const int lane = t & 63;
    const int w    = t >> 6;              // wave 0..7, owns f/e-slice [64w, 64w+64)
    const int r16  = lane & 15;
    const int q4   = (lane >> 4) * 4;
    const long base = (long)b * 64 * 512;

    // zero score accumulator buffer (atomics target)
    for (int i = t; i < 64 * SP; i += 512) sS[i] = 0.f;

    // ---- mean-chunk staging: global -> regs (2-deep) -> LDS (fp16) ----
    const int mrow = t >> 3;              // 0..63 (h)
    const int me0  = (t & 7) * 4;         // 8 threads x 4 f32 = 32 e
    float4_t ogA[3], ogB[3];

    auto issue = [&](int c, float4_t (&og)[3]) {
        const long off = base + (long)mrow * 512 + c * EC + me0;
        og[0] = *(const float4_t*)(o1 + off);
        og[1] = *(const float4_t*)(o2 + off);
        og[2] = *(const float4_t*)(o3 + off);
    };
    auto commit = [&](int buf, float4_t (&og)[3]) {
        float4_t m = (og[0] + og[1] + og[2]) * (1.0f / 3.0f);
        half4_t h;
        h[0]=(_Float16)m[0]; h[1]=(_Float16)m[1]; h[2]=(_Float16)m[2]; h[3]=(_Float16)m[3];
        *(half4_t*)(&sM[buf][mrow * MP + me0]) = h;
    };

    // ---- phase 1: U^T tiles = W^T @ M^T, K=512 over e, accumulate in regs ----
    // accU[ftl][ht] holds U[ht*16+r16][w*64+ftl*16+q4+j]  (== phase-2 A-frag)
    float4_t accU[4][4];
    #pragma unroll
    for (int i = 0; i < 4; ++i)
        #pragma unroll
        for (int j = 0; j < 4; ++j) accU[i][j] = (float4_t){0,0,0,0};

    auto compute_chunk = [&](int c, int bufc) {
        #pragma unroll
        for (int kk = 0; kk < 2; ++kk) {
            const int ks = c * 2 + kk;
            half4_t A[4], Bm[4];
            #pragma unroll
            for (int ftl = 0; ftl < 4; ++ftl)
                A[ftl] = *(const half4_t*)(W2 + (((long)(w * 4 + ftl) * 32 + ks) * 64 + lane) * 4);
            #pragma unroll
            for (int ht = 0; ht < 4; ++ht)
                Bm[ht] = *(const half4_t*)(&sM[bufc][(ht * 16 + r16) * MP + kk * 16 + q4]);
            #pragma unroll
            for (int ftl = 0; ftl < 4; ++ftl)
                #pragma unroll
                for (int ht = 0; ht < 4; ++ht)
                    accU[ftl][ht] = MFMA16(A[ftl], Bm[ht], accU[ftl][ht]);
        }
    };

    // prologue: chunks 0 and 1 in flight; commit chunk 0
    issue(0, ogA);
    issue(1, ogB);
    commit(0, ogA);                 // waits only ogA loads; ogB stays in flight
    __syncthreads();

    // steady state: commit of chunk c+1 waits loads issued ~2 iterations earlier
    for (int cc = 0; cc < NCH; cc += 2) {
        // even chunk cc (in sM[0], regs ogA free after its commit)
        if (cc + 2 < NCH) issue(cc + 2, ogA);
        compute_chunk(cc, 0);
        commit(1, ogB);             // chunk cc+1 -> sM[1]
        __syncthreads();
        // odd chunk cc+1 (in sM[1])
        if (cc + 3 < NCH) issue(cc + 3, ogB);
        compute_chunk(cc + 1, 1);
        if (cc + 2 < NCH) commit(0, ogA);   // chunk cc+2 -> sM[0]
        __syncthreads();
    }

    // ---- phase 2: score partial = U_slice @ Q^T (K = 64 over wave's f-slice) ----
    half4_t uh[4][4];
    #pragma unroll
    for (int ftl = 0; ftl < 4; ++ftl)
        #pragma unroll
        for (int ht = 0; ht < 4; ++ht) {
            half4_t h;
            h[0]=(_Float16)accU[ftl][ht][0]; h[1]=(_Float16)accU[ftl][ht][1];
            h[2]=(_Float16)accU[ftl][ht][2]; h[3]=(_Float16)accU[ftl][ht][3];
            uh[ftl][ht] = h;
        }

    float4_t sc[4][4];   // [ht][gt]
    #pragma unroll
    for (int i = 0; i < 4; ++i)
        #pragma unroll
        for (int j = 0; j < 4; ++j) sc[i][j] = (float4_t){0,0,0,0};

    #pragma unroll
    for (int ftl = 0; ftl < 4; ++ftl) {
        half4_t Bq[4];
        #pragma unroll
        for (int gt = 0; gt < 4; ++gt) {
            float4_t qv = *(const float4_t*)(qm + base + (long)(gt * 16 + r16) * 512
                                             + w * 64 + ftl * 16 + q4);
            half4_t h;
            h[0]=(_Float16)qv[0]; h[1]=(_Float16)qv[1]; h[2]=(_Float16)qv[2]; h[3]=(_Float16)qv[3];
            Bq[gt] = h;
        }
        #pragma unroll
        for (int ht = 0; ht < 4; ++ht)
            #pragma unroll
            for (int gt = 0; gt < 4; ++gt)
                sc[ht][gt] = MFMA16(uh[ftl][ht], Bq[gt], sc[ht][gt]);
    }

    // cross-wave reduction into sS
    #pragma unroll
    for (int ht = 0; ht < 4; ++ht)
        #pragma unroll
        for (int gt = 0; gt < 4; ++gt)
            #pragma unroll
            for (int j = 0; j < 4; ++j)
                atomicAdd(&sS[(ht * 16 + q4 + j) * SP + gt * 16 + r16], sc[ht][gt][j]);
    __syncthreads();

    // ---- softmax over g (waves 0-3: 16 rows each, 4 lanes/row) ----
    if (w < 4) {
        const int r  = w * 16 + r16;
        const int qd = lane >> 4;
        const float* srow = sS + r * SP + qd * 16;
        float v[16];
        float mx = -1e30f;
        #pragma unroll
        for (int i = 0; i < 16; ++i) { v[i] = srow[i]; mx = fmaxf(mx, v[i]); }
        mx = fmaxf(mx, __shfl_xor(mx, 16));
        mx = fmaxf(mx, __shfl_xor(mx, 32));
        float sum = 0.f;
        #pragma unroll
        for (int i = 0; i < 16; ++i) { v[i] = __expf(v[i] - mx); sum += v[i]; }
        sum += __shfl_xor(sum, 16);
        sum += __shfl_xor(sum, 32);
        const float inv = 1.0f / sum;
        float*    aout = out + CTX + ((long)b * 64 + r) * 64 + qd * 16;
        _Float16* prow = sP + r * PP + qd * 16;
        #pragma unroll
        for (int i = 0; i < 16; ++i) {
            float a = v[i] * inv;
            aout[i] = a;
            prow[i] = (_Float16)a;
        }
    }
    __syncthreads();

    // ---- phase 3: context = P @ Q, wave w owns e-slice [64w, 64w+64) ----
    float4_t acc[4][4];   // [ht][et]
    #pragma unroll
    for (int i = 0; i < 4; ++i)
        #pragma unroll
        for (int j = 0; j < 4; ++j) acc[i][j] = (float4_t){0,0,0,0};

    const int Eb = w * 64;
    #pragma unroll
    for (int kk = 0; kk < 4; ++kk) {
        half4_t aP[4], bQ[4];
        #pragma unroll
        for (int ht = 0; ht < 4; ++ht)
            aP[ht] = *(const half4_t*)(&sP[(ht * 16 + r16) * PP + kk * 16 + q4]);
        #pragma unroll
        for (int et = 0; et < 4; ++et) {
            half4_t h;
            #pragma unroll
            for (int j = 0; j < 4; ++j)
                h[j] = (_Float16)qm[base + (long)(kk * 16 + q4 + j) * 512 + Eb + et * 16 + r16];
            bQ[et] = h;
        }
        #pragma unroll
        for (int ht = 0; ht < 4; ++ht)
            #pragma unroll
            for (int et = 0; et < 4; ++et)
                acc[ht][et] = MFMA16(aP[ht], bQ[et], acc[ht][et]);
    }

    // ---- store context (f32) ----
    #pragma unroll
    for (int ht = 0; ht < 4; ++ht)
        #pragma unroll
        for (int j = 0; j < 4; ++j) {
            const long row = (long)b * 64 + ht * 16 + q4 + j;
            float* orow = out + row * 512 + Eb;
            #pragma unroll
            for (int et = 0; et < 4; ++et)
                orow[et * 16 + r16] = acc[ht][et][j];
        }
}

extern "C" void kernel_launch(void* const* d_in, const int* in_sizes, int n_in,
                              void* d_out, int out_size, void* d_ws, size_t ws_size,
                              hipStream_t stream) {
    const float* o1 = (const float*)d_in[0];
    const float* o2 = (const float*)d_in[1];
    const float* o3 = (const float*)d_in[2];
    const float* qm = (const float*)d_in[3];
    const float* W  = (const float*)d_in[4];
    float* out = (float*)d_out;
    _Float16* W2 = (_Float16*)d_ws;       // 512 KB fragment-layout fp16 W

    w_pack<<<dim3(256), dim3(256), 0, stream>>>(W, W2);
    ovo_main<<<dim3(Bb), dim3(512), 0, stream>>>(o1, o2, o3, qm, W2, out);
}

// Round 5
// 218.427 us; speedup vs baseline: 1.8572x; 1.8572x over previous
//
#include <hip/hip_runtime.h>
#include <hip/hip_bf16.h>

typedef _Float16 half4_t __attribute__((ext_vector_type(4)));
typedef _Float16 half8_t __attribute__((ext_vector_type(8)));
typedef float    float4_t __attribute__((ext_vector_type(4)));

#define MFMA32(a, b, c) __builtin_amdgcn_mfma_f32_16x16x32_f16((a), (b), (c), 0, 0, 0)

constexpr int  Bb  = 1024;
constexpr long CTX = (long)Bb * 64 * 512;      // attn offset in d_out
constexpr int  SVP = 520;                      // sV row stride (halves)
constexpr int  SQP = 40;                       // sQc row stride (halves)
constexpr int  QTP = 72;                       // qT row stride (halves)

// ---- pre-pass: pack W (f32 [e][f]) into A-fragment layout fp16 ----
// frag (E=e-tile 0..31, c=f-chunk 0..15): W2[(E*16+c)*512 + lane*8 + j]
//   = W[E*16 + (lane&15)][c*32 + (lane>>4)*8 + j]
__global__ void w_pack(const float* __restrict__ W, _Float16* __restrict__ W2) {
    const int t = blockIdx.x * 256 + threadIdx.x;      // 32768 threads
    const int lane = t & 63, grp = t >> 6;             // grp 0..511
    const int E = grp >> 4, c = grp & 15;
    const int r16 = lane & 15, q = lane >> 4;
    const float* src = W + (long)(E * 16 + r16) * 512 + c * 32 + q * 8;
    float4_t x = *(const float4_t*)(src);
    float4_t y = *(const float4_t*)(src + 4);
    half8_t h;
    h[0]=(_Float16)x[0]; h[1]=(_Float16)x[1]; h[2]=(_Float16)x[2]; h[3]=(_Float16)x[3];
    h[4]=(_Float16)y[0]; h[5]=(_Float16)y[1]; h[6]=(_Float16)y[2]; h[7]=(_Float16)y[3];
    *(half8_t*)(W2 + (long)t * 8) = h;
}

// ---- kernel A: V = W*q^T (LDS), then score = M*V streamed, softmax -> attn ----
__global__ __launch_bounds__(512, 4)
void ovo_score(const float* __restrict__ o1, const float* __restrict__ o2,
               const float* __restrict__ o3, const float* __restrict__ qm,
               const _Float16* __restrict__ W2, float* __restrict__ out)
{
    __shared__ __align__(16) _Float16 sV[64 * SVP];      // V^T [g][e]  66.5 KB
    __shared__ __align__(16) _Float16 sQc[2][64 * SQP];  // q f-chunk [g][32] x2  10 KB

    const int t = threadIdx.x, lane = t & 63, w = t >> 6;
    const int r16 = lane & 15, q = lane >> 4;
    const long base = (long)blockIdx.x * 64 * 512;
    const float4_t zf4 = {0.f, 0.f, 0.f, 0.f};

    // ================= phase V: V = W * q^T =================
    // q-chunk staging map: row g = t>>3 (0..63), f-quad = t&7
    const int sg = t >> 3, sf4 = t & 7;
    const float* qsrc = qm + base + (long)sg * 512 + sf4 * 4;

    float4_t qA, qB;
    auto qcommit = [&](int buf, const float4_t& v) {
        half4_t h;
        h[0]=(_Float16)v[0]; h[1]=(_Float16)v[1]; h[2]=(_Float16)v[2]; h[3]=(_Float16)v[3];
        *(half4_t*)(&sQc[buf][sg * SQP + sf4 * 4]) = h;
    };

    float4_t vacc[4][4];   // [et][gt]
    #pragma unroll
    for (int i = 0; i < 4; ++i)
        #pragma unroll
        for (int j = 0; j < 4; ++j) vacc[i][j] = zf4;

    auto vcompute = [&](int c, int buf) {
        half8_t Bq[4];
        #pragma unroll
        for (int gt = 0; gt < 4; ++gt)
            Bq[gt] = *(const half8_t*)(&sQc[buf][(gt * 16 + r16) * SQP + q * 8]);
        #pragma unroll
        for (int et = 0; et < 4; ++et) {
            const int E = w * 4 + et;
            half8_t A = *(const half8_t*)(W2 + (long)(E * 16 + c) * 512 + lane * 8);
            #pragma unroll
            for (int gt = 0; gt < 4; ++gt)
                vacc[et][gt] = MFMA32(A, Bq[gt], vacc[et][gt]);
        }
    };

    qA = *(const float4_t*)(qsrc + 0);
    qcommit(0, qA);
    __syncthreads();
    #pragma unroll
    for (int cc = 0; cc < 16; cc += 2) {
        qB = *(const float4_t*)(qsrc + (cc + 1) * 32);
        vcompute(cc, 0);
        qcommit(1, qB);
        __syncthreads();
        if (cc + 2 < 16) qA = *(const float4_t*)(qsrc + (cc + 2) * 32);
        vcompute(cc + 1, 1);
        if (cc + 2 < 16) qcommit(0, qA);
        __syncthreads();
    }

    // write V^T to LDS: lane holds V[e = E*16 + q*4 + r][g = gt*16 + r16]
    #pragma unroll
    for (int et = 0; et < 4; ++et) {
        const int e0 = w * 64 + et * 16 + q * 4;
        #pragma unroll
        for (int gt = 0; gt < 4; ++gt)
            #pragma unroll
            for (int r = 0; r < 4; ++r)
                sV[(gt * 16 + r16) * SVP + e0 + r] = (_Float16)vacc[et][gt][r];
    }
    __syncthreads();

    // ================= phase S: score = M * V (streamed, no barriers) =================
    const int ht = w & 3, eh = w >> 2;           // h-tile, e-half
    const long abase = base + (long)(ht * 16 + r16) * 512 + eh * 256 + q * 8;
    const int esV = eh * 256 + q * 8;

    float4_t sacc[4];
    #pragma unroll
    for (int i = 0; i < 4; ++i) sacc[i] = zf4;

    float4_t a1A, b1A, a2A, b2A, a3A, b3A;       // set A (chunk c)
    float4_t a1B, b1B, a2B, b2B, a3B, b3B;       // set B (chunk c+1)

    #define SLOAD(S, c) do { \
        const long o_ = abase + (c) * 32; \
        a1##S = *(const float4_t*)(o1 + o_); b1##S = *(const float4_t*)(o1 + o_ + 4); \
        a2##S = *(const float4_t*)(o2 + o_); b2##S = *(const float4_t*)(o2 + o_ + 4); \
        a3##S = *(const float4_t*)(o3 + o_); b3##S = *(const float4_t*)(o3 + o_ + 4); \
    } while (0)

    #define SCOMP(S, c) do { \
        float4_t m0 = (a1##S + a2##S + a3##S) * (1.0f / 3.0f); \
        float4_t m1 = (b1##S + b2##S + b3##S) * (1.0f / 3.0f); \
        half8_t af; \
        af[0]=(_Float16)m0[0]; af[1]=(_Float16)m0[1]; af[2]=(_Float16)m0[2]; af[3]=(_Float16)m0[3]; \
        af[4]=(_Float16)m1[0]; af[5]=(_Float16)m1[1]; af[6]=(_Float16)m1[2]; af[7]=(_Float16)m1[3]; \
        _Pragma("unroll") \
        for (int gt = 0; gt < 4; ++gt) { \
            half8_t bf = *(const half8_t*)(&sV[(gt * 16 + r16) * SVP + esV + (c) * 32]); \
            sacc[gt] = MFMA32(af, bf, sacc[gt]); \
        } \
    } while (0)

    SLOAD(A, 0);
    #pragma unroll
    for (int cc = 0; cc < 8; cc += 2) {
        SLOAD(B, cc + 1);
        SCOMP(A, cc);
        if (cc + 2 < 8) SLOAD(A, cc + 2);
        SCOMP(B, cc + 1);
    }

    // ================= reduce e-halves + softmax (in regs) =================
    __syncthreads();                              // all sV reads done
    float* part = reinterpret_cast<float*>(sV);   // 16 KB overlay
    if (w >= 4) {
        #pragma unroll
        for (int gt = 0; gt < 4; ++gt)
            *(float4_t*)(&part[(((w - 4) * 4 + gt) * 64 + lane) * 4]) = sacc[gt];
    }
    __syncthreads();
    if (w < 4) {
        #pragma unroll
        for (int gt = 0; gt < 4; ++gt)
            sacc[gt] += *(const float4_t*)(&part[((w * 4 + gt) * 64 + lane) * 4]);
        #pragma unroll
        for (int r = 0; r < 4; ++r) {
            float mx = fmaxf(fmaxf(sacc[0][r], sacc[1][r]), fmaxf(sacc[2][r], sacc[3][r]));
            mx = fmaxf(mx, __shfl_xor(mx, 1));
            mx = fmaxf(mx, __shfl_xor(mx, 2));
            mx = fmaxf(mx, __shfl_xor(mx, 4));
            mx = fmaxf(mx, __shfl_xor(mx, 8));
            float p0 = __expf(sacc[0][r] - mx), p1 = __expf(sacc[1][r] - mx);
            float p2 = __expf(sacc[2][r] - mx), p3 = __expf(sacc[3][r] - mx);
            float s = p0 + p1 + p2 + p3;
            s += __shfl_xor(s, 1); s += __shfl_xor(s, 2);
            s += __shfl_xor(s, 4); s += __shfl_xor(s, 8);
            const float inv = 1.0f / s;
            float* arow = out + CTX + ((long)blockIdx.x * 64 + w * 16 + q * 4 + r) * 64;
            arow[ 0 + r16] = p0 * inv;
            arow[16 + r16] = p1 * inv;
            arow[32 + r16] = p2 * inv;
            arow[48 + r16] = p3 * inv;
        }
    }
}

// ---- kernel B: context = attn @ q (chunked LDS transpose of q) ----
__global__ __launch_bounds__(256, 4)
void ovo_ctx(const float* __restrict__ qm, const float* __restrict__ out_attn,
             float* __restrict__ out)
{
    __shared__ __align__(16) _Float16 qT[2][64 * QTP];   // q^T chunk [e][g]  36 KB

    const int t = threadIdx.x, lane = t & 63, w = t >> 6;   // 4 waves = 4 h-tiles
    const int r16 = lane & 15, q = lane >> 4;
    const long b = blockIdx.x;
    const long base = b * 64 * 512;
    const float4_t zf4 = {0.f, 0.f, 0.f, 0.f};

    // A-frags: attn rows h = w*16 + r16, k = kh*32 + q*8 + j (f32 -> f16)
    const float* ap = out_attn + (b * 64 + w * 16 + r16) * 64 + q * 8;
    half8_t pA0, pA1;
    {
        float4_t x = *(const float4_t*)(ap + 0),  y = *(const float4_t*)(ap + 4);
        pA0[0]=(_Float16)x[0]; pA0[1]=(_Float16)x[1]; pA0[2]=(_Float16)x[2]; pA0[3]=(_Float16)x[3];
        pA0[4]=(_Float16)y[0]; pA0[5]=(_Float16)y[1]; pA0[6]=(_Float16)y[2]; pA0[7]=(_Float16)y[3];
        float4_t z = *(const float4_t*)(ap + 32), u = *(const float4_t*)(ap + 36);
        pA1[0]=(_Float16)z[0]; pA1[1]=(_Float16)z[1]; pA1[2]=(_Float16)z[2]; pA1[3]=(_Float16)z[3];
        pA1[4]=(_Float16)u[0]; pA1[5]=(_Float16)u[1]; pA1[6]=(_Float16)u[2]; pA1[7]=(_Float16)u[3];
    }

    // staging map: g = t&63, e16 = (t>>6)*16; 16 consecutive e per thread
    const int sg = t & 63, se = (t >> 6) * 16;
    const float* qsrc = qm + base + (long)sg * 512 + se;
    float4_t rA[4], rB[4];

    #define QLOAD(R, c) do { \
        _Pragma("unroll") \
        for (int i = 0; i < 4; ++i) R[i] = *(const float4_t*)(qsrc + (c) * 64 + i * 4); \
    } while (0)
    #define QCOMMIT(R, buf) do { \
        _Pragma("unroll") \
        for (int i = 0; i < 4; ++i) \
            _Pragma("unroll") \
            for (int jj = 0; jj < 4; ++jj) \
                qT[buf][(se + i * 4 + jj) * QTP + sg] = (_Float16)R[i][jj]; \
    } while (0)

    #define BCOMP(c, buf) do { \
        _Pragma("unroll") \
        for (int et = 0; et < 4; ++et) { \
            half8_t b0 = *(const half8_t*)(&qT[buf][(et * 16 + r16) * QTP + q * 8]); \
            half8_t b1 = *(const half8_t*)(&qT[buf][(et * 16 + r16) * QTP + 32 + q * 8]); \
            float4_t acc = MFMA32(pA0, b0, zf4); \
            acc = MFMA32(pA1, b1, acc); \
            _Pragma("unroll") \
            for (int rr = 0; rr < 4; ++rr) \
                out[(b * 64 + w * 16 + q * 4 + rr) * 512 + (c) * 64 + et * 16 + r16] = acc[rr]; \
        } \
    } while (0)

    QLOAD(rA, 0);
    QCOMMIT(rA, 0);
    __syncthreads();
    #pragma unroll
    for (int cc = 0; cc < 8; cc += 2) {
        QLOAD(rB, cc + 1);
        BCOMP(cc, 0);
        QCOMMIT(rB, 1);
        __syncthreads();
        if (cc + 2 < 8) QLOAD(rA, cc + 2);
        BCOMP(cc + 1, 1);
        if (cc + 2 < 8) QCOMMIT(rA, 0);
        __syncthreads();
    }
}

extern "C" void kernel_launch(void* const* d_in, const int* in_sizes, int n_in,
                              void* d_out, int out_size, void* d_ws, size_t ws_size,
                              hipStream_t stream) {
    const float* o1 = (const float*)d_in[0];
    const float* o2 = (const float*)d_in[1];
    const float* o3 = (const float*)d_in[2];
    const float* qm = (const float*)d_in[3];
    const float* W  = (const float*)d_in[4];
    float* out = (float*)d_out;
    _Float16* W2 = (_Float16*)d_ws;           // 512 KB fragment-layout fp16 W

    w_pack<<<dim3(128), dim3(256), 0, stream>>>(W, W2);
    ovo_score<<<dim3(Bb), dim3(512), 0, stream>>>(o1, o2, o3, qm, W2, out);
    ovo_ctx<<<dim3(Bb), dim3(256), 0, stream>>>(qm, out + CTX, out);
}

// Round 6
// 211.615 us; speedup vs baseline: 1.9170x; 1.0322x over previous
//
#include <hip/hip_runtime.h>
#include <hip/hip_bf16.h>

typedef _Float16 half4_t __attribute__((ext_vector_type(4)));
typedef _Float16 half8_t __attribute__((ext_vector_type(8)));
typedef float    float4_t __attribute__((ext_vector_type(4)));

#define MFMA32(a, b, c) __builtin_amdgcn_mfma_f32_16x16x32_f16((a), (b), (c), 0, 0, 0)

constexpr int  Bb  = 1024;
constexpr long CTX = (long)Bb * 64 * 512;      // attn offset in d_out
constexpr int  SQP = 520;                      // shared q/V^T row stride (halves)
constexpr int  QTP = 72;                       // qT row stride (halves), kernel B

// ---- pre-pass: pack W (f32 [e][f]) into fragment layout fp16 ----
// W2[(E*16+c)*512 + lane*8 + j] = W[E*16 + (lane&15)][c*32 + (lane>>4)*8 + j]
// Serves as B-frag (k=f, n=e) for V^T = q*W^T in phase V.
__global__ void w_pack(const float* __restrict__ W, _Float16* __restrict__ W2) {
    const int t = blockIdx.x * 256 + threadIdx.x;      // 32768 threads
    const int lane = t & 63, grp = t >> 6;             // grp 0..511
    const int E = grp >> 4, c = grp & 15;
    const int r16 = lane & 15, q = lane >> 4;
    const float* src = W + (long)(E * 16 + r16) * 512 + c * 32 + q * 8;
    float4_t x = *(const float4_t*)(src);
    float4_t y = *(const float4_t*)(src + 4);
    half8_t h;
    h[0]=(_Float16)x[0]; h[1]=(_Float16)x[1]; h[2]=(_Float16)x[2]; h[3]=(_Float16)x[3];
    h[4]=(_Float16)y[0]; h[5]=(_Float16)y[1]; h[6]=(_Float16)y[2]; h[7]=(_Float16)y[3];
    *(half8_t*)(W2 + (long)t * 8) = h;
}

// ---- kernel A: stage q -> LDS; V^T = q*W^T (no barriers); V^T overwrites q;
//      score = M*V streamed; softmax -> attn ----
__global__ __launch_bounds__(512, 4)
void ovo_score(const float* __restrict__ o1, const float* __restrict__ o2,
               const float* __restrict__ o3, const float* __restrict__ qm,
               const _Float16* __restrict__ W2, float* __restrict__ out)
{
    __shared__ __align__(16) _Float16 sQ[64 * SQP];   // q fp16 [g][f], later V^T [g][e]; 66.6 KB

    const int t = threadIdx.x, lane = t & 63, w = t >> 6;
    const int r16 = lane & 15, q = lane >> 4;
    const long base = (long)blockIdx.x * 64 * 512;
    const float4_t zf4 = {0.f, 0.f, 0.f, 0.f};

    // ---- stage q (fp16) once: 8 threads/row, coalesced dwordx4, all loads independent ----
    {
        const int srow = t >> 3;              // 0..63 (g)
        const int sf   = (t & 7) * 4;         // col base
        const float* qsrc = qm + base + (long)srow * 512 + sf;
        _Float16*    qdst = &sQ[srow * SQP + sf];
        #pragma unroll
        for (int k = 0; k < 16; ++k) {
            float4_t v = *(const float4_t*)(qsrc + k * 32);
            half4_t h;
            h[0]=(_Float16)v[0]; h[1]=(_Float16)v[1]; h[2]=(_Float16)v[2]; h[3]=(_Float16)v[3];
            *(half4_t*)(qdst + k * 32) = h;
        }
    }
    __syncthreads();

    // ---- phase V: V^T[g][e] = sum_f q[g,f] * W[e,f]; wave w owns e-slice [64w,64w+64) ----
    // A-frag = q (m=g, k=f) from LDS; B-frag = W2 (k=f, n=e) from global (L2).
    float4_t vacc[4][4];   // [gt][et]
    #pragma unroll
    for (int i = 0; i < 4; ++i)
        #pragma unroll
        for (int j = 0; j < 4; ++j) vacc[i][j] = zf4;

    #pragma unroll
    for (int c = 0; c < 16; ++c) {
        half8_t Aq[4], Bw[4];
        #pragma unroll
        for (int gt = 0; gt < 4; ++gt)
            Aq[gt] = *(const half8_t*)(&sQ[(gt * 16 + r16) * SQP + c * 32 + q * 8]);
        #pragma unroll
        for (int et = 0; et < 4; ++et)
            Bw[et] = *(const half8_t*)(W2 + (long)((w * 4 + et) * 16 + c) * 512 + lane * 8);
        #pragma unroll
        for (int gt = 0; gt < 4; ++gt)
            #pragma unroll
            for (int et = 0; et < 4; ++et)
                vacc[gt][et] = MFMA32(Aq[gt], Bw[et], vacc[gt][et]);
    }

    // ---- q dead: overwrite sQ with V^T [g][e] ----
    __syncthreads();
    #pragma unroll
    for (int gt = 0; gt < 4; ++gt)
        #pragma unroll
        for (int et = 0; et < 4; ++et)
            #pragma unroll
            for (int r = 0; r < 4; ++r)
                sQ[(gt * 16 + q * 4 + r) * SQP + w * 64 + et * 16 + r16] =
                    (_Float16)vacc[gt][et][r];
    __syncthreads();

    // ---- phase S: score = M * V (streamed, no barriers) ----
    const int ht = w & 3, eh = w >> 2;           // h-tile, e-half
    const long abase = base + (long)(ht * 16 + r16) * 512 + eh * 256 + q * 8;
    const int esV = eh * 256 + q * 8;

    float4_t sacc[4];
    #pragma unroll
    for (int i = 0; i < 4; ++i) sacc[i] = zf4;

    float4_t a1A, b1A, a2A, b2A, a3A, b3A;       // set A (chunk c)
    float4_t a1B, b1B, a2B, b2B, a3B, b3B;       // set B (chunk c+1)

    #define SLOAD(S, c) do { \
        const long o_ = abase + (c) * 32; \
        a1##S = *(const float4_t*)(o1 + o_); b1##S = *(const float4_t*)(o1 + o_ + 4); \
        a2##S = *(const float4_t*)(o2 + o_); b2##S = *(const float4_t*)(o2 + o_ + 4); \
        a3##S = *(const float4_t*)(o3 + o_); b3##S = *(const float4_t*)(o3 + o_ + 4); \
    } while (0)

    #define SCOMP(S, c) do { \
        float4_t m0 = (a1##S + a2##S + a3##S) * (1.0f / 3.0f); \
        float4_t m1 = (b1##S + b2##S + b3##S) * (1.0f / 3.0f); \
        half8_t af; \
        af[0]=(_Float16)m0[0]; af[1]=(_Float16)m0[1]; af[2]=(_Float16)m0[2]; af[3]=(_Float16)m0[3]; \
        af[4]=(_Float16)m1[0]; af[5]=(_Float16)m1[1]; af[6]=(_Float16)m1[2]; af[7]=(_Float16)m1[3]; \
        _Pragma("unroll") \
        for (int gt = 0; gt < 4; ++gt) { \
            half8_t bf = *(const half8_t*)(&sQ[(gt * 16 + r16) * SQP + esV + (c) * 32]); \
            sacc[gt] = MFMA32(af, bf, sacc[gt]); \
        } \
    } while (0)

    SLOAD(A, 0);
    #pragma unroll
    for (int cc = 0; cc < 8; cc += 2) {
        SLOAD(B, cc + 1);
        SCOMP(A, cc);
        if (cc + 2 < 8) SLOAD(A, cc + 2);
        SCOMP(B, cc + 1);
    }

    // ---- reduce e-halves + softmax (in regs) ----
    __syncthreads();                              // all sQ (V^T) reads done
    float* part = reinterpret_cast<float*>(sQ);   // 16 KB overlay
    if (w >= 4) {
        #pragma unroll
        for (int gt = 0; gt < 4; ++gt)
            *(float4_t*)(&part[(((w - 4) * 4 + gt) * 64 + lane) * 4]) = sacc[gt];
    }
    __syncthreads();
    if (w < 4) {
        #pragma unroll
        for (int gt = 0; gt < 4; ++gt)
            sacc[gt] += *(const float4_t*)(&part[((w * 4 + gt) * 64 + lane) * 4]);
        #pragma unroll
        for (int r = 0; r < 4; ++r) {
            float mx = fmaxf(fmaxf(sacc[0][r], sacc[1][r]), fmaxf(sacc[2][r], sacc[3][r]));
            mx = fmaxf(mx, __shfl_xor(mx, 1));
            mx = fmaxf(mx, __shfl_xor(mx, 2));
            mx = fmaxf(mx, __shfl_xor(mx, 4));
            mx = fmaxf(mx, __shfl_xor(mx, 8));
            float p0 = __expf(sacc[0][r] - mx), p1 = __expf(sacc[1][r] - mx);
            float p2 = __expf(sacc[2][r] - mx), p3 = __expf(sacc[3][r] - mx);
            float s = p0 + p1 + p2 + p3;
            s += __shfl_xor(s, 1); s += __shfl_xor(s, 2);
            s += __shfl_xor(s, 4); s += __shfl_xor(s, 8);
            const float inv = 1.0f / s;
            float* arow = out + CTX + ((long)blockIdx.x * 64 + w * 16 + q * 4 + r) * 64;
            arow[ 0 + r16] = p0 * inv;
            arow[16 + r16] = p1 * inv;
            arow[32 + r16] = p2 * inv;
            arow[48 + r16] = p3 * inv;
        }
    }
}

// ---- kernel B: context = attn @ q (chunked LDS transpose of q) ----
__global__ __launch_bounds__(256, 4)
void ovo_ctx(const float* __restrict__ qm, const float* __restrict__ out_attn,
             float* __restrict__ out)
{
    __shared__ __align__(16) _Float16 qT[2][64 * QTP];   // q^T chunk [e][g]  36 KB

    const int t = threadIdx.x, lane = t & 63, w = t >> 6;   // 4 waves = 4 h-tiles
    const int r16 = lane & 15, q = lane >> 4;
    const long b = blockIdx.x;
    const long base = b * 64 * 512;
    const float4_t zf4 = {0.f, 0.f, 0.f, 0.f};

    // A-frags: attn rows h = w*16 + r16, k = kh*32 + q*8 + j (f32 -> f16)
    const float* ap = out_attn + (b * 64 + w * 16 + r16) * 64 + q * 8;
    half8_t pA0, pA1;
    {
        float4_t x = *(const float4_t*)(ap + 0),  y = *(const float4_t*)(ap + 4);
        pA0[0]=(_Float16)x[0]; pA0[1]=(_Float16)x[1]; pA0[2]=(_Float16)x[2]; pA0[3]=(_Float16)x[3];
        pA0[4]=(_Float16)y[0]; pA0[5]=(_Float16)y[1]; pA0[6]=(_Float16)y[2]; pA0[7]=(_Float16)y[3];
        float4_t z = *(const float4_t*)(ap + 32), u = *(const float4_t*)(ap + 36);
        pA1[0]=(_Float16)z[0]; pA1[1]=(_Float16)z[1]; pA1[2]=(_Float16)z[2]; pA1[3]=(_Float16)z[3];
        pA1[4]=(_Float16)u[0]; pA1[5]=(_Float16)u[1]; pA1[6]=(_Float16)u[2]; pA1[7]=(_Float16)u[3];
    }

    // staging map: g = t&63, e16 = (t>>6)*16; 16 consecutive e per thread
    const int sg = t & 63, se = (t >> 6) * 16;
    const float* qsrc = qm + base + (long)sg * 512 + se;
    float4_t rA[4], rB[4];

    #define QLOAD(R, c) do { \
        _Pragma("unroll") \
        for (int i = 0; i < 4; ++i) R[i] = *(const float4_t*)(qsrc + (c) * 64 + i * 4); \
    } while (0)
    #define QCOMMIT(R, buf) do { \
        _Pragma("unroll") \
        for (int i = 0; i < 4; ++i) \
            _Pragma("unroll") \
            for (int jj = 0; jj < 4; ++jj) \
                qT[buf][(se + i * 4 + jj) * QTP + sg] = (_Float16)R[i][jj]; \
    } while (0)

    #define BCOMP(c, buf) do { \
        _Pragma("unroll") \
        for (int et = 0; et < 4; ++et) { \
            half8_t b0 = *(const half8_t*)(&qT[buf][(et * 16 + r16) * QTP + q * 8]); \
            half8_t b1 = *(const half8_t*)(&qT[buf][(et * 16 + r16) * QTP + 32 + q * 8]); \
            float4_t acc = MFMA32(pA0, b0, zf4); \
            acc = MFMA32(pA1, b1, acc); \
            _Pragma("unroll") \
            for (int rr = 0; rr < 4; ++rr) \
                out[(b * 64 + w * 16 + q * 4 + rr) * 512 + (c) * 64 + et * 16 + r16] = acc[rr]; \
        } \
    } while (0)

    QLOAD(rA, 0);
    QCOMMIT(rA, 0);
    __syncthreads();
    #pragma unroll
    for (int cc = 0; cc < 8; cc += 2) {
        QLOAD(rB, cc + 1);
        BCOMP(cc, 0);
        QCOMMIT(rB, 1);
        __syncthreads();
        if (cc + 2 < 8) QLOAD(rA, cc + 2);
        BCOMP(cc + 1, 1);
        if (cc + 2 < 8) QCOMMIT(rA, 0);
        __syncthreads();
    }
}

extern "C" void kernel_launch(void* const* d_in, const int* in_sizes, int n_in,
                              void* d_out, int out_size, void* d_ws, size_t ws_size,
                              hipStream_t stream) {
    const float* o1 = (const float*)d_in[0];
    const float* o2 = (const float*)d_in[1];
    const float* o3 = (const float*)d_in[2];
    const float* qm = (const float*)d_in[3];
    const float* W  = (const float*)d_in[4];
    float* out = (float*)d_out;
    _Float16* W2 = (_Float16*)d_ws;           // 512 KB fragment-layout fp16 W

    w_pack<<<dim3(128), dim3(256), 0, stream>>>(W, W2);
    ovo_score<<<dim3(Bb), dim3(512), 0, stream>>>(o1, o2, o3, qm, W2, out);
    ovo_ctx<<<dim3(Bb), dim3(256), 0, stream>>>(qm, out + CTX, out);
}